// Round 8
// baseline (679.929 us; speedup 1.0000x reference)
//
#include <hip/hip_runtime.h>
#include <math.h>

// Problem constants
#define BATCH 16
#define CH    64
#define HDIM  256
#define WDIM  256
#define HW    65536        // 256*256
#define KS    7
#define HIDN  16
#define COUT  3136         // CH * KS * KS
#define NPLANE 1024        // BATCH * CH

// float4 with relaxed (4B) alignment for the shifted staging loads
typedef float4 f4u __attribute__((aligned(4)));

// ---------------------------------------------------------------------------
// Kernel 1: global average pool (unchanged from baseline)
// ---------------------------------------------------------------------------
__global__ __launch_bounds__(512) void gap_kernel(const float* __restrict__ x,
                                                  float* __restrict__ pooled) {
    const int p = blockIdx.x;
    const float4* xv = (const float4*)(x + (size_t)p * HW);
    const int t = threadIdx.x;
    float s = 0.f;
    #pragma unroll 4
    for (int i = t; i < 16384; i += 512) {
        float4 a = xv[i];
        s += (a.x + a.y) + (a.z + a.w);
    }
    #pragma unroll
    for (int off = 32; off > 0; off >>= 1) s += __shfl_down(s, off);
    __shared__ float sp[8];
    const int wid = t >> 6, lane = t & 63;
    if (lane == 0) sp[wid] = s;
    __syncthreads();
    if (t == 0) {
        float tot = 0.f;
        #pragma unroll
        for (int i = 0; i < 8; ++i) tot += sp[i];
        pooled[p] = tot * (1.0f / 65536.0f);
    }
}

// ---------------------------------------------------------------------------
// Kernel 2: MLP weight generator (unchanged from baseline)
// ---------------------------------------------------------------------------
__global__ __launch_bounds__(256) void mlp_kernel(const float* __restrict__ pooled,
                                                  const float* __restrict__ w1,
                                                  const float* __restrict__ b1,
                                                  const float* __restrict__ w2,
                                                  const float* __restrict__ b2,
                                                  float* __restrict__ wout) {
    __shared__ float s_pool[NPLANE];
    __shared__ float s_hdn[BATCH * HIDN];
    const int t = threadIdx.x;
    for (int i = t; i < NPLANE; i += 256) s_pool[i] = pooled[i];
    __syncthreads();
    {
        const int i = t >> 4, j = t & 15;
        float acc = b1[j];
        #pragma unroll
        for (int c = 0; c < 64; ++c) acc += s_pool[i * 64 + c] * w1[c * HIDN + j];
        s_hdn[t] = 0.5f * acc * (1.0f + erff(acc * 0.70710678118654752f));
    }
    __syncthreads();
    const int o = blockIdx.x * 256 + t;
    const int i = o / COUT;
    const int j = o - i * COUT;
    float acc = b2[j];
    #pragma unroll
    for (int h = 0; h < HIDN; ++h) acc += s_hdn[i * HIDN + h] * w2[h * COUT + j];
    wout[o] = 1.0f / (1.0f + expf(-acc));
}

// ---------------------------------------------------------------------------
// Kernel 3: depthwise 7x7 conv, reflect pad, dynamic per-plane weights.
//
// Memory config = R5/R7 (clean traffic: WRITE 1.0x, VGPR 84 non-spill point).
// R7 diagnosis: conv ~160us vs ~55us/SIMD issue floor => 65% no-issue stalls
// (exposed global-load latency at each block's single stage->barrier).
//
// This round: PERSISTENT blocks with cross-plane prefetch (T14 across tiles).
// Grid (2,4,256); each block keeps its (bx,by) tile and processes NP=4
// consecutive DESCENDING planes p = 1023-4*z-i (preserves R7's reverse-order
// L3 reuse; bijective). Per-thread global offsets are plane-independent:
// computed ONCE; per plane only pbase changes.
//   loop i: {commit regs->LDS; barrier; issue plane i+1 loads (fly under
//            compute); compute plane i from LDS; store; barrier}
// Exposed latency: once per block (4 tiles) instead of every tile, and the
// vmcnt wait for the prefetch lands a full compute-phase after issue.
// Register budget ~120 (off9+toff6+v36+tv6+acc32+misc) < (256,3) cap 170.
// ---------------------------------------------------------------------------
#define TLX 128
#define TLY 64
#define INY 70             // TLY + 6
#define LDSS 136           // padded LDS row stride (floats), 544B, 16B-aligned
#define NP   4             // planes per block

__global__ __launch_bounds__(256, 3) void conv_kernel(const float* __restrict__ x,
                                                      const float* __restrict__ wts,
                                                      float* __restrict__ out) {
    __shared__ float s_in[INY * LDSS];
    __shared__ float s_w[49];
    const int t   = threadIdx.x;
    const int gx0 = blockIdx.x * TLX;
    const int gy0 = blockIdx.y * TLY - 3;
    const int zb  = blockIdx.z;            // 0..255

    // left-edge reversal applies to threads with c4==0 when bx==0, for ALL k
    // (i & 31 == t & 31 since 256k = 0 mod 32)
    const bool rev = (gx0 == 0) && ((t & 31) == 0);

    // ---- plane-independent per-thread offsets (elements) ----
    int off[9];
    #pragma unroll
    for (int k = 0; k < 9; ++k) {
        const int r = (t >> 5) + 8 * k;    // row 0..71 (k==8 valid if t<192)
        int gy = gy0 + r;
        gy = gy < 0 ? -gy : (gy > 255 ? 510 - gy : gy);
        const int c4 = (t & 31) << 2;
        const int gxs = rev ? 0 : (gx0 - 3 + c4);
        off[k] = gy * WDIM + gxs;
    }
    int toff[6];
    if (t < INY) {
        int gy = gy0 + t;
        gy = gy < 0 ? -gy : (gy > 255 ? 510 - gy : gy);
        #pragma unroll
        for (int j = 0; j < 6; ++j) {
            int gx = gx0 - 3 + 128 + j;
            gx = gx > 255 ? 510 - gx : gx;
            toff[j] = gy * WDIM + gx;
        }
    }

    // ---- prologue: prefetch plane i=0 into registers ----
    float4 v[9];
    float  tv[6];
    float  wv = 0.f;
    {
        const int p0 = (NPLANE - 1) - 4 * zb;
        const size_t pb = (size_t)p0 * HW;
        #pragma unroll
        for (int k = 0; k < 9; ++k)
            if (k < 8 || t < 192) v[k] = *(const f4u*)(x + pb + off[k]);
        if (t < INY) {
            #pragma unroll
            for (int j = 0; j < 6; ++j) tv[j] = x[pb + toff[j]];
        }
        if (t < 49) wv = wts[p0 * 49 + t];
    }

    for (int i = 0; i < NP; ++i) {
        const int p = (NPLANE - 1) - 4 * zb - i;
        const size_t pbase = (size_t)p * HW;

        // ---- commit prefetched registers to LDS ----
        #pragma unroll
        for (int k = 0; k < 9; ++k) {
            if (k < 8 || t < 192) {
                const int r  = (t >> 5) + 8 * k;
                const int c4 = (t & 31) << 2;
                float4 sv = v[k];
                if (rev) sv = make_float4(v[k].w, v[k].z, v[k].y, v[k].x);
                *(float4*)&s_in[r * LDSS + c4] = sv;
            }
        }
        if (t < INY) {
            #pragma unroll
            for (int j = 0; j < 6; ++j) s_in[t * LDSS + 128 + j] = tv[j];
        }
        if (t < 49) s_w[t] = wv;
        __syncthreads();

        // ---- issue next plane's loads (fly under the compute below) ----
        if (i + 1 < NP) {
            const size_t nb = (size_t)(p - 1) * HW;
            #pragma unroll
            for (int k = 0; k < 9; ++k)
                if (k < 8 || t < 192) v[k] = *(const f4u*)(x + nb + off[k]);
            if (t < INY) {
                #pragma unroll
                for (int j = 0; j < 6; ++j) tv[j] = x[nb + toff[j]];
            }
            if (t < 49) wv = wts[(p - 1) * 49 + t];
        }

        // ---- compute current plane from LDS ----
        float w[49];
        #pragma unroll
        for (int q = 0; q < 49; ++q) w[q] = s_w[q];

        const int tx4 = (t & 31) * 4;
        const int ty  = (t >> 5) * 8;

        float acc[32];
        #pragma unroll
        for (int q = 0; q < 32; ++q) acc[q] = 0.f;

        #pragma unroll
        for (int r = 0; r < 14; ++r) {
            const float* rp = &s_in[(ty + r) * LDSS + tx4];
            const float4 v0 = *(const float4*)(rp);
            const float4 v1 = *(const float4*)(rp + 4);
            const float4 v2 = *(const float4*)(rp + 8);
            const float row[12] = {v0.x, v0.y, v0.z, v0.w,
                                   v1.x, v1.y, v1.z, v1.w,
                                   v2.x, v2.y, v2.z, v2.w};
            #pragma unroll
            for (int o = 0; o < 8; ++o) {
                const int ky = r - o;
                if (ky < 0 || ky > 6) continue;      // compile-time resolved
                #pragma unroll
                for (int kx = 0; kx < 7; ++kx) {
                    const float wvv = w[ky * 7 + kx];
                    acc[o * 4 + 0] += wvv * row[kx + 0];
                    acc[o * 4 + 1] += wvv * row[kx + 1];
                    acc[o * 4 + 2] += wvv * row[kx + 2];
                    acc[o * 4 + 3] += wvv * row[kx + 3];
                }
            }
        }

        const int oy0 = blockIdx.y * TLY + ty;
        const int ox  = gx0 + tx4;
        #pragma unroll
        for (int o = 0; o < 8; ++o) {
            const float4 vv = make_float4(acc[o * 4 + 0], acc[o * 4 + 1],
                                          acc[o * 4 + 2], acc[o * 4 + 3]);
            *(float4*)&out[pbase + (size_t)(oy0 + o) * WDIM + ox] = vv;
        }
        __syncthreads();   // LDS free for next iteration's commit
    }
}

// ---------------------------------------------------------------------------
extern "C" void kernel_launch(void* const* d_in, const int* in_sizes, int n_in,
                              void* d_out, int out_size, void* d_ws, size_t ws_size,
                              hipStream_t stream) {
    const float* x  = (const float*)d_in[0];
    const float* w1 = (const float*)d_in[1];
    const float* b1 = (const float*)d_in[2];
    const float* w2 = (const float*)d_in[3];
    const float* b2 = (const float*)d_in[4];
    float* out = (float*)d_out;

    float* pooled = (float*)d_ws;           // 1024 floats
    float* wts    = pooled + NPLANE;        // 50176 floats

    gap_kernel<<<NPLANE, 512, 0, stream>>>(x, pooled);
    mlp_kernel<<<(BATCH * COUT) / 256, 256, 0, stream>>>(pooled, w1, b1, w2, b2, wts);
    conv_kernel<<<dim3(WDIM / TLX, HDIM / TLY, NPLANE / NP), 256, 0, stream>>>(x, wts, out);
}